// Round 6
// baseline (52.617 us; speedup 1.0000x reference)
//
#include <hip/hip_runtime.h>

typedef __attribute__((ext_vector_type(8))) short bf16x8;
typedef __attribute__((ext_vector_type(4))) float f32x4;
typedef __attribute__((ext_vector_type(2))) float f32x2;

__device__ __forceinline__ f32x2 fma2(f32x2 a, f32x2 b, f32x2 c) {
    return __builtin_elementwise_fma(a, b, c);   // llvm.fma.v2f32 -> v_pk_fma_f32
}

// quad_perm DPP (VALU cross-lane, no DS pipe). CTRL = perm[0]|perm[1]<<2|perm[2]<<4|perm[3]<<6
// 0x141 = row_half_mirror (lane i -> i^7 within each octet).
template <int CTRL>
__device__ __forceinline__ float qperm(float x) {
    return __builtin_bit_cast(float,
        __builtin_amdgcn_update_dpp(0, __builtin_bit_cast(int, x), CTRL, 0xf, 0xf, true));
}
template <int CTRL>
__device__ __forceinline__ f32x2 qperm2(f32x2 x) {
    f32x2 r;
    r.x = qperm<CTRL>(x.x);
    r.y = qperm<CTRL>(x.y);
    return r;
}

// Fused: quantum-head encode + 8x8 head-attention + scrambled reshape + 64x64 combine.
// Lane map: lane = kch(2b) : G1(1b) : h(3b); each aligned 8-lane group = one token's
// 8 heads; each lane's attention output IS its MFMA A-fragment slot.
// R6: packed-f32 (v_pk_fma_f32) QSTEP math on float2 pairs; fract+v_cos with folded
// 1/2pi+theta FMA; softmax scale kappa=sqrt(alpha*log2 e) folded into c[1], 1/kappa
// folded into staged W; 4096 blocks x 2 iters.
__global__ __launch_bounds__(256) void qattn(const float* __restrict__ x,
                                             const float* __restrict__ theta,
                                             const float* __restrict__ wc,
                                             const float* __restrict__ bc,
                                             float* __restrict__ out)
{
    // [snt=4*s+nt][lane][8] ushorts, 8 KB each; fragments pre-permuted so the
    // b128 read addr = base + lane*16 (linear, wave-uniform base).
    __shared__ __align__(16) unsigned short sWhi[512 * 8];
    __shared__ __align__(16) unsigned short sWlo[512 * 8];

    const float KAPPA = 0.71419161f;        // sqrt(2^-1.5 * log2(e))
    const float INVK  = 1.40018590f;        // 1/KAPPA
    const float INV2PI = 0.15915494309189535f;

    const int tid = threadIdx.x;
    #pragma unroll
    for (int f0 = 0; f0 < 2; ++f0) {
        const int f = tid * 2 + f0;          // 0..511
        const int snt = f >> 6, ln = f & 63;
        const int s = snt >> 2, nt = snt & 3;
        const int r = nt * 16 + (ln & 15);
        const int koff = s * 32 + (ln >> 4) * 8;
        const float* wp = wc + r * 64 + koff;
        float w8[8];
        *(float4*)(&w8[0]) = *(const float4*)(wp);
        *(float4*)(&w8[4]) = *(const float4*)(wp + 4);
        #pragma unroll
        for (int j = 0; j < 8; ++j) {
            float w = w8[j] * INVK;          // fold 1/kappa into W
            unsigned u = __builtin_bit_cast(unsigned, w);
            sWhi[f * 8 + j] = (unsigned short)(u >> 16);
            float rhi = __builtin_bit_cast(float, u & 0xffff0000u);
            unsigned l = __builtin_bit_cast(unsigned, w - rhi);
            sWlo[f * 8 + j] = (unsigned short)(l >> 16);
        }
    }
    __syncthreads();

    const int lane = tid & 63;
    const int wid  = tid >> 6;
    const int h    = lane & 7;
    const int G1   = (lane >> 3) & 1;
    const int kch  = lane >> 4;
    const int col  = lane & 15;
    const int fby  = lane * 8;

    // theta/(2pi) packed pairs
    f32x2 th2p[4];
    #pragma unroll
    for (int j = 0; j < 4; ++j) {
        th2p[j].x = theta[2 * j] * INV2PI;
        th2p[j].y = theta[2 * j + 1] * INV2PI;
    }
    float bs[4];
    #pragma unroll
    for (int nt = 0; nt < 4; ++nt) bs[nt] = bc[nt * 16 + col];

    const int P0 = (int)blockIdx.x * 4 + wid;            // 0..16383
    const float* xp0 = x + ((size_t)((2 * P0 + G1) * 8 + kch)) * 64 + h * 8;
    const size_t IT_STRIDE = (size_t)16384 * 16 * 64;    // pairs * tokens * E

    float4 cur[4];
    cur[0] = *(const float4*)(xp0);
    cur[1] = *(const float4*)(xp0 + 4);
    cur[2] = *(const float4*)(xp0 + 256);
    cur[3] = *(const float4*)(xp0 + 260);

    #pragma unroll
    for (int it = 0; it < 2; ++it) {
        float4 nxt[4];
        if (it < 1) {
            const float* p = xp0 + IT_STRIDE;
            nxt[0] = *(const float4*)(p);
            nxt[1] = *(const float4*)(p + 4);
            nxt[2] = *(const float4*)(p + 256);
            nxt[3] = *(const float4*)(p + 260);
        }

        const int P = it * 16384 + P0;   // group-pair 0..32767

        bf16x8 ahi[2], alo[2];
        #pragma unroll
        for (int s = 0; s < 2; ++s) {
            // angle in revolutions: a = fma(v, 1/2pi, th/2pi), packed
            const f32x2* v2 = (const f32x2*)&cur[s * 2];
            f32x2 inv2 = {INV2PI, INV2PI};
            float c[8];
            #pragma unroll
            for (int j = 0; j < 4; ++j) {
                f32x2 a2 = fma2(v2[j], inv2, th2p[j]);
                c[2 * j]     = __builtin_amdgcn_cosf(__builtin_amdgcn_fractf(a2.x));
                c[2 * j + 1] = __builtin_amdgcn_cosf(__builtin_amdgcn_fractf(a2.y));
            }
            c[1] *= KAPPA;   // every z contains c1 -> scales all z by kappa

            // z[0] = c1..c7 ; z[k] = c0..ck (k>=1)   (all pre-scaled by kappa)
            float z[8];
            z[1] = c[0] * c[1];
            #pragma unroll
            for (int d = 2; d < 8; ++d) z[d] = z[d - 1] * c[d];
            float p = c[1];
            #pragma unroll
            for (int d = 2; d < 8; ++d) p *= c[d];
            z[0] = p;

            f32x2 z2[4];
            #pragma unroll
            for (int j = 0; j < 4; ++j) { z2[j].x = z[2 * j]; z2[j].y = z[2 * j + 1]; }

            // partner at t = h^7 via row_half_mirror
            f32x2 z72[4];
            #pragma unroll
            for (int j = 0; j < 4; ++j) z72[j] = qperm2<0x141>(z2[j]);

            f32x2 osum2[4];
            #pragma unroll
            for (int j = 0; j < 4; ++j) osum2[j] = (f32x2){0.f, 0.f};
            float esum = 0.f;

            // packed softmax-PV step vs partner pair-vector zt2
            #define QSTEP(ZT)                                                      \
                do {                                                               \
                    f32x2 s2 = (ZT)[0] * z2[0];                                    \
                    s2 = fma2((ZT)[1], z2[1], s2);                                 \
                    s2 = fma2((ZT)[2], z2[2], s2);                                 \
                    s2 = fma2((ZT)[3], z2[3], s2);                                 \
                    float e = __builtin_amdgcn_exp2f(s2.x + s2.y);                 \
                    esum += e;                                                     \
                    f32x2 e2 = {e, e};                                             \
                    _Pragma("unroll")                                              \
                    for (int j = 0; j < 4; ++j)                                    \
                        osum2[j] = fma2(e2, (ZT)[j], osum2[j]);                    \
                } while (0)

            QSTEP(z2);                                           // m=0
            {
                f32x2 w2[4];
                #pragma unroll
                for (int j = 0; j < 4; ++j) w2[j] = qperm2<0xB1>(z2[j]);   // m=1
                QSTEP(w2);
                #pragma unroll
                for (int j = 0; j < 4; ++j) w2[j] = qperm2<0x4E>(z2[j]);   // m=2
                QSTEP(w2);
                #pragma unroll
                for (int j = 0; j < 4; ++j) w2[j] = qperm2<0x1B>(z2[j]);   // m=3
                QSTEP(w2);
            }
            QSTEP(z72);                                          // m=7
            {
                f32x2 w2[4];
                #pragma unroll
                for (int j = 0; j < 4; ++j) w2[j] = qperm2<0xB1>(z72[j]);  // m=6
                QSTEP(w2);
                #pragma unroll
                for (int j = 0; j < 4; ++j) w2[j] = qperm2<0x4E>(z72[j]);  // m=5
                QSTEP(w2);
                #pragma unroll
                for (int j = 0; j < 4; ++j) w2[j] = qperm2<0x1B>(z72[j]);  // m=4
                QSTEP(w2);
            }
            #undef QSTEP

            float r = __builtin_amdgcn_rcpf(esum);
            f32x2 r2 = {r, r};
            f32x2 o2[4];
            #pragma unroll
            for (int j = 0; j < 4; ++j) o2[j] = osum2[j] * r2;

            // truncation hi/lo split + pair pack (o includes kappa; W has 1/kappa)
            unsigned hp[4], lp[4];
            #pragma unroll
            for (int pq = 0; pq < 4; ++pq) {
                unsigned e0 = __builtin_bit_cast(unsigned, o2[pq].x);
                unsigned e1 = __builtin_bit_cast(unsigned, o2[pq].y);
                hp[pq] = (e0 >> 16) | (e1 & 0xffff0000u);
                float r0 = __builtin_bit_cast(float, e0 & 0xffff0000u);
                float r1 = __builtin_bit_cast(float, e1 & 0xffff0000u);
                unsigned l0 = __builtin_bit_cast(unsigned, o2[pq].x - r0);
                unsigned l1 = __builtin_bit_cast(unsigned, o2[pq].y - r1);
                lp[pq] = (l0 >> 16) | (l1 & 0xffff0000u);
            }
            ahi[s] = __builtin_bit_cast(bf16x8, *(const unsigned(*)[4])hp);
            alo[s] = __builtin_bit_cast(bf16x8, *(const unsigned(*)[4])lp);
        }

        #pragma unroll
        for (int q = 0; q < 4; ++q) cur[q] = nxt[q];

        // Y(16x64) = G(16x64) @ (W/k)^T via 4 n-tiles x 2 k-chunks x 3 passes (hi/lo).
        f32x4 acc[4];
        #pragma unroll
        for (int nt = 0; nt < 4; ++nt) acc[nt] = (f32x4){0.f, 0.f, 0.f, 0.f};
        #pragma unroll
        for (int nt = 0; nt < 4; ++nt) {
            #pragma unroll
            for (int s = 0; s < 2; ++s) {
                const int off = (s * 4 + nt) * 512 + fby;
                bf16x8 bhi = *(const bf16x8*)(&sWhi[off]);
                bf16x8 blo = *(const bf16x8*)(&sWlo[off]);
                acc[nt] = __builtin_amdgcn_mfma_f32_16x16x32_bf16(ahi[s], bhi, acc[nt], 0, 0, 0);
                acc[nt] = __builtin_amdgcn_mfma_f32_16x16x32_bf16(alo[s], bhi, acc[nt], 0, 0, 0);
                acc[nt] = __builtin_amdgcn_mfma_f32_16x16x32_bf16(ahi[s], blo, acc[nt], 0, 0, 0);
            }
        }

        // C/D: col = lane&15, row = (lane>>4)*4 + q ; row -> (G1', h'),
        // output row = b*8192 + h'*1024 + g_in_batch.
        #pragma unroll
        for (int q = 0; q < 4; ++q) {
            const int r16 = kch * 4 + q;
            const int hh = r16 & 7;
            const int gg = r16 >> 3;
            const int gf2 = 2 * P + gg;
            const int orow = (gf2 >> 10) * 8192 + hh * 1024 + (gf2 & 1023);
            float* op = out + orow * 64 + col;
            #pragma unroll
            for (int nt = 0; nt < 4; ++nt)
                op[nt * 16] = acc[nt][q] + bs[nt];
        }
    }
}

extern "C" void kernel_launch(void* const* d_in, const int* in_sizes, int n_in,
                              void* d_out, int out_size, void* d_ws, size_t ws_size,
                              hipStream_t stream) {
    const float* x     = (const float*)d_in[0];
    const float* theta = (const float*)d_in[1];
    const float* wc    = (const float*)d_in[2];
    const float* bc    = (const float*)d_in[3];
    float* out = (float*)d_out;
    qattn<<<dim3(4096), dim3(256), 0, stream>>>(x, theta, wc, bc, out);
}